// Round 5
// baseline (682.190 us; speedup 1.0000x reference)
//
#include <hip/hip_runtime.h>
#include <math.h>

#define DDIM 1024
#define BQ 256
#define EPSV 1e-8f
#define CH 4
#define TPC 16
#define NCAND (CH * TPC)

typedef short bf16x8 __attribute__((ext_vector_type(8)));
typedef float f32x4 __attribute__((ext_vector_type(4)));

__device__ __forceinline__ unsigned short f2bf(float x) {
  union { float f; unsigned int u; } v;
  v.f = x;
  unsigned int lsb = (v.u >> 16) & 1u;
  v.u += 0x7fffu + lsb;  // round-to-nearest-even
  return (unsigned short)(v.u >> 16);
}
__device__ __forceinline__ float bf2f(unsigned short b) {
  union { unsigned int u; float f; } v;
  v.u = ((unsigned int)b) << 16;
  return v.f;
}
// packed fp32->bf16 (RNE), 1 instr for 2 elements: low16=bf16(lo), hi16=bf16(hi)
__device__ __forceinline__ unsigned int cvtpk_bf16(float lo, float hi) {
  unsigned int r;
  asm("v_cvt_pk_bf16_f32 %0, %1, %2" : "=v"(r) : "v"(lo), "v"(hi));
  return r;
}

// ---------------- prep: Q fp32 -> bf16 in MFMA-fragment order, qn ----------
// Qb layout: 16-B chunks. chunk = (t*16 + q/16)*64 + kquad*16 + (q&15),
// where t = k/32, kquad = (k/8)&3, elem = k&7. With this order, the gemm
// wave's fragment load group (t, g=w*4+i) has lane l reading chunk
// group*64 + l  == one contiguous, perfectly coalesced 1 KB per wave.
__global__ __launch_bounds__(256) void prep_q(const float* __restrict__ Q,
                                              unsigned short* __restrict__ Qb,
                                              float* __restrict__ qn) {
  int wave = threadIdx.x >> 6, lane = threadIdx.x & 63;
  int q = blockIdx.x * 4 + wave;
  const float4* src = (const float4*)(Q + (size_t)q * DDIM);
  int g = q >> 4, qrow = q & 15;
  float s = 0.f;
#pragma unroll
  for (int t4 = 0; t4 < 4; ++t4) {
    float4 v = src[t4 * 64 + lane];
    s += v.x * v.x + v.y * v.y + v.z * v.z + v.w * v.w;
    int k = t4 * 256 + lane * 4;
    int tt = k >> 5;
    int kquad = (k >> 3) & 3;
    int elem = k & 7;  // 0 or 4
    size_t chunk = (size_t)(tt * 16 + g) * 64 + kquad * 16 + qrow;
    ushort4 o;
    o.x = f2bf(v.x); o.y = f2bf(v.y); o.z = f2bf(v.z); o.w = f2bf(v.w);
    *(ushort4*)(Qb + chunk * 8 + elem) = o;
  }
#pragma unroll
  for (int o = 32; o > 0; o >>= 1) s += __shfl_down(s, o, 64);
  if (lane == 0) qn[q] = sqrtf(s);
}

// ---------------- MFMA GEMM: 256 q x 128 n per block ----------------
// BN=128: half the blocks/barrier-steps of BN=64, half the Q L2 traffic,
// 2x MFMA per barrier. Q direct from L2-resident fragment-ordered Qb into
// registers (double-buffered, 1-step prefetch); M reg-staged with 2-step
// prefetch -> LDS (double-buffered 8 KB tiles). One raw barrier per K-step;
// compiler-visible loads keep counted vmcnt automatic (prefetches stay in
// flight across the barrier). Epilogue folds 1/||m|| into stored bf16 cos.
__global__ __launch_bounds__(256, 2) void gemm_topk(
    const float* __restrict__ M, const unsigned short* __restrict__ Qb,
    unsigned short* __restrict__ sims, int N, int Npitch) {
  __shared__ unsigned short Ms[2][128 * 32];  // [buf][n][k], 8 KB each
  __shared__ float rls[128];                  // 1/||m|| for this block's rows
  const int tid = threadIdx.x;
  const int wave = tid >> 6, lane = tid & 63;
  const int quad = lane >> 4, l15 = lane & 15;
  const int n0 = blockIdx.x * 128;

  const int mrow = tid >> 1;       // 0..127
  const int mc = (tid & 1) * 16;   // float offset in the 32-float k-slab
  const bool mvalid = (n0 + mrow) < N;
  // invalid rows redirect to row 0: keeps vmem issue counts wave-uniform;
  // resulting sims at n>=N land in the pitch padding and are never read.
  const float* mptr = M + (size_t)(mvalid ? (n0 + mrow) : 0) * DDIM + mc;

  // fragment pointer: afr(t, i) = qptr[t*1024 + i*64]
  const bf16x8* qptr = (const bf16x8*)Qb + (size_t)wave * 256 + lane;

  f32x4 acc[4][8];
#pragma unroll
  for (int i = 0; i < 4; ++i)
#pragma unroll
    for (int j = 0; j < 8; ++j) acc[i][j] = (f32x4){0.f, 0.f, 0.f, 0.f};
  float sumsq = 0.f;

  // prologue: Q(0) fragments + M(0), M(1) into named reg sets.
  bf16x8 aA0 = qptr[0], aA1 = qptr[64], aA2 = qptr[128], aA3 = qptr[192];
  bf16x8 aB0{}, aB1{}, aB2{}, aB3{};  // filled by body(0) before body(1) reads
  float4 mrA0 = *(const float4*)(mptr);
  float4 mrA1 = *(const float4*)(mptr + 4);
  float4 mrA2 = *(const float4*)(mptr + 8);
  float4 mrA3 = *(const float4*)(mptr + 12);
  float4 mrB0 = *(const float4*)(mptr + 32);
  float4 mrB1 = *(const float4*)(mptr + 36);
  float4 mrB2 = *(const float4*)(mptr + 40);
  float4 mrB3 = *(const float4*)(mptr + 44);

  auto body = [&](int t, int buf, float4& r0, float4& r1, float4& r2,
                  float4& r3, bf16x8& c0, bf16x8& c1, bf16x8& c2, bf16x8& c3,
                  bf16x8& p0, bf16x8& p1, bf16x8& p2, bf16x8& p3) {
    // ---- convert M(t) -> Ms[buf], sumsq, prefetch M(t+2) ----
    sumsq += r0.x * r0.x + r0.y * r0.y + r0.z * r0.z + r0.w * r0.w +
             r1.x * r1.x + r1.y * r1.y + r1.z * r1.z + r1.w * r1.w +
             r2.x * r2.x + r2.y * r2.y + r2.z * r2.z + r2.w * r2.w +
             r3.x * r3.x + r3.y * r3.y + r3.z * r3.z + r3.w * r3.w;
    uint4 pk0, pk1;
    pk0.x = cvtpk_bf16(r0.x, r0.y);
    pk0.y = cvtpk_bf16(r0.z, r0.w);
    pk0.z = cvtpk_bf16(r1.x, r1.y);
    pk0.w = cvtpk_bf16(r1.z, r1.w);
    pk1.x = cvtpk_bf16(r2.x, r2.y);
    pk1.y = cvtpk_bf16(r2.z, r2.w);
    pk1.z = cvtpk_bf16(r3.x, r3.y);
    pk1.w = cvtpk_bf16(r3.z, r3.w);
    *(uint4*)&Ms[buf][mrow * 32 + mc] = pk0;
    *(uint4*)&Ms[buf][mrow * 32 + mc + 8] = pk1;
    int k2 = t * 32 + 64;
    const float* p = mptr + ((k2 < DDIM) ? k2 : 0);  // dummy keeps count uniform
    r0 = *(const float4*)(p);
    r1 = *(const float4*)(p + 4);
    r2 = *(const float4*)(p + 8);
    r3 = *(const float4*)(p + 12);
    // ---- Ms[buf] visible to all waves; prefetches stay in flight ----
    asm volatile("s_waitcnt lgkmcnt(0)" ::: "memory");
    __builtin_amdgcn_s_barrier();
    __builtin_amdgcn_sched_barrier(0);
    // ---- prefetch Q(t+1) fragments (dummy reload of group 0 at t=31) ----
    const bf16x8* qp = qptr + (size_t)((t + 1) & 31) * 1024;
    p0 = qp[0]; p1 = qp[64]; p2 = qp[128]; p3 = qp[192];
    // ---- compute on buf; two j-quads to cap bfr liveness ----
    {
      bf16x8 bfr0 = *(const bf16x8*)&Ms[buf][(0 * 16 + l15) * 32 + quad * 8];
      bf16x8 bfr1 = *(const bf16x8*)&Ms[buf][(1 * 16 + l15) * 32 + quad * 8];
      bf16x8 bfr2 = *(const bf16x8*)&Ms[buf][(2 * 16 + l15) * 32 + quad * 8];
      bf16x8 bfr3 = *(const bf16x8*)&Ms[buf][(3 * 16 + l15) * 32 + quad * 8];
      acc[0][0] = __builtin_amdgcn_mfma_f32_16x16x32_bf16(c0, bfr0, acc[0][0], 0, 0, 0);
      acc[0][1] = __builtin_amdgcn_mfma_f32_16x16x32_bf16(c0, bfr1, acc[0][1], 0, 0, 0);
      acc[0][2] = __builtin_amdgcn_mfma_f32_16x16x32_bf16(c0, bfr2, acc[0][2], 0, 0, 0);
      acc[0][3] = __builtin_amdgcn_mfma_f32_16x16x32_bf16(c0, bfr3, acc[0][3], 0, 0, 0);
      acc[1][0] = __builtin_amdgcn_mfma_f32_16x16x32_bf16(c1, bfr0, acc[1][0], 0, 0, 0);
      acc[1][1] = __builtin_amdgcn_mfma_f32_16x16x32_bf16(c1, bfr1, acc[1][1], 0, 0, 0);
      acc[1][2] = __builtin_amdgcn_mfma_f32_16x16x32_bf16(c1, bfr2, acc[1][2], 0, 0, 0);
      acc[1][3] = __builtin_amdgcn_mfma_f32_16x16x32_bf16(c1, bfr3, acc[1][3], 0, 0, 0);
      acc[2][0] = __builtin_amdgcn_mfma_f32_16x16x32_bf16(c2, bfr0, acc[2][0], 0, 0, 0);
      acc[2][1] = __builtin_amdgcn_mfma_f32_16x16x32_bf16(c2, bfr1, acc[2][1], 0, 0, 0);
      acc[2][2] = __builtin_amdgcn_mfma_f32_16x16x32_bf16(c2, bfr2, acc[2][2], 0, 0, 0);
      acc[2][3] = __builtin_amdgcn_mfma_f32_16x16x32_bf16(c2, bfr3, acc[2][3], 0, 0, 0);
      acc[3][0] = __builtin_amdgcn_mfma_f32_16x16x32_bf16(c3, bfr0, acc[3][0], 0, 0, 0);
      acc[3][1] = __builtin_amdgcn_mfma_f32_16x16x32_bf16(c3, bfr1, acc[3][1], 0, 0, 0);
      acc[3][2] = __builtin_amdgcn_mfma_f32_16x16x32_bf16(c3, bfr2, acc[3][2], 0, 0, 0);
      acc[3][3] = __builtin_amdgcn_mfma_f32_16x16x32_bf16(c3, bfr3, acc[3][3], 0, 0, 0);
    }
    {
      bf16x8 bfr4 = *(const bf16x8*)&Ms[buf][(4 * 16 + l15) * 32 + quad * 8];
      bf16x8 bfr5 = *(const bf16x8*)&Ms[buf][(5 * 16 + l15) * 32 + quad * 8];
      bf16x8 bfr6 = *(const bf16x8*)&Ms[buf][(6 * 16 + l15) * 32 + quad * 8];
      bf16x8 bfr7 = *(const bf16x8*)&Ms[buf][(7 * 16 + l15) * 32 + quad * 8];
      acc[0][4] = __builtin_amdgcn_mfma_f32_16x16x32_bf16(c0, bfr4, acc[0][4], 0, 0, 0);
      acc[0][5] = __builtin_amdgcn_mfma_f32_16x16x32_bf16(c0, bfr5, acc[0][5], 0, 0, 0);
      acc[0][6] = __builtin_amdgcn_mfma_f32_16x16x32_bf16(c0, bfr6, acc[0][6], 0, 0, 0);
      acc[0][7] = __builtin_amdgcn_mfma_f32_16x16x32_bf16(c0, bfr7, acc[0][7], 0, 0, 0);
      acc[1][4] = __builtin_amdgcn_mfma_f32_16x16x32_bf16(c1, bfr4, acc[1][4], 0, 0, 0);
      acc[1][5] = __builtin_amdgcn_mfma_f32_16x16x32_bf16(c1, bfr5, acc[1][5], 0, 0, 0);
      acc[1][6] = __builtin_amdgcn_mfma_f32_16x16x32_bf16(c1, bfr6, acc[1][6], 0, 0, 0);
      acc[1][7] = __builtin_amdgcn_mfma_f32_16x16x32_bf16(c1, bfr7, acc[1][7], 0, 0, 0);
      acc[2][4] = __builtin_amdgcn_mfma_f32_16x16x32_bf16(c2, bfr4, acc[2][4], 0, 0, 0);
      acc[2][5] = __builtin_amdgcn_mfma_f32_16x16x32_bf16(c2, bfr5, acc[2][5], 0, 0, 0);
      acc[2][6] = __builtin_amdgcn_mfma_f32_16x16x32_bf16(c2, bfr6, acc[2][6], 0, 0, 0);
      acc[2][7] = __builtin_amdgcn_mfma_f32_16x16x32_bf16(c2, bfr7, acc[2][7], 0, 0, 0);
      acc[3][4] = __builtin_amdgcn_mfma_f32_16x16x32_bf16(c3, bfr4, acc[3][4], 0, 0, 0);
      acc[3][5] = __builtin_amdgcn_mfma_f32_16x16x32_bf16(c3, bfr5, acc[3][5], 0, 0, 0);
      acc[3][6] = __builtin_amdgcn_mfma_f32_16x16x32_bf16(c3, bfr6, acc[3][6], 0, 0, 0);
      acc[3][7] = __builtin_amdgcn_mfma_f32_16x16x32_bf16(c3, bfr7, acc[3][7], 0, 0, 0);
    }
  };

#pragma unroll 1
  for (int t = 0; t < 32; t += 2) {
    body(t, 0, mrA0, mrA1, mrA2, mrA3, aA0, aA1, aA2, aA3, aB0, aB1, aB2, aB3);
    body(t + 1, 1, mrB0, mrB1, mrB2, mrB3, aB0, aB1, aB2, aB3, aA0, aA1, aA2, aA3);
  }

  // 1/||m|| per row (each row's 32-float slabs owned by thread pair tid,tid^1)
  float s = sumsq + __shfl_xor(sumsq, 1, 64);
  if ((tid & 1) == 0) rls[mrow] = (s > 0.f) ? rsqrtf(s) : 0.f;
  __syncthreads();

  // store bf16 cosines (dot * 1/||m||; per-q 1/||q|| scaling doesn't change
  // per-q ranking, and rescore recomputes exact fp32 cos)
#pragma unroll
  for (int j = 0; j < 8; ++j) {
    float rm = rls[j * 16 + l15];
#pragma unroll
    for (int i = 0; i < 4; ++i)
#pragma unroll
      for (int r = 0; r < 4; ++r) {
        int q = wave * 64 + i * 16 + quad * 4 + r;
        int n = n0 + j * 16 + l15;
        sims[(size_t)q * Npitch + n] = f2bf(acc[i][j][r] * rm);
      }
  }
}

// ---------------- helpers ----------------
__device__ __forceinline__ bool better(float v1, int i1, float v2, int i2) {
  return v1 > v2 || (v1 == v2 && i1 < i2);
}

template <int L>
__device__ __forceinline__ void insert_topL(float (&tv)[L], int (&ti)[L],
                                            float v, int idx) {
  if (v > tv[L - 1] || (v == tv[L - 1] && idx < ti[L - 1])) {
    tv[L - 1] = v; ti[L - 1] = idx;
#pragma unroll
    for (int j = L - 1; j > 0; --j) {
      if (better(tv[j], ti[j], tv[j - 1], ti[j - 1])) {
        float fv = tv[j]; tv[j] = tv[j - 1]; tv[j - 1] = fv;
        int ii = ti[j]; ti[j] = ti[j - 1]; ti[j - 1] = ii;
      }
    }
  }
}

// block tournament (blockDim=256): extract `rounds` best entries across
// per-thread sorted lists of length L.
template <int L, typename F>
__device__ __forceinline__ void block_extract(float (&tv)[L], int (&ti)[L],
                                              int rounds, F&& emit) {
  __shared__ float s_v[4];
  __shared__ int s_i[4];
  __shared__ int s_t[4];
  __shared__ float s_wv;
  __shared__ int s_wi;
  __shared__ int s_wt;
  for (int r = 0; r < rounds; ++r) {
    float v = tv[0];
    int idx = ti[0];
    int src = threadIdx.x;
#pragma unroll
    for (int o = 32; o > 0; o >>= 1) {
      float ov = __shfl_down(v, o, 64);
      int oi = __shfl_down(idx, o, 64);
      int os = __shfl_down(src, o, 64);
      if (better(ov, oi, v, idx)) { v = ov; idx = oi; src = os; }
    }
    int lane = threadIdx.x & 63, w = threadIdx.x >> 6;
    if (lane == 0) { s_v[w] = v; s_i[w] = idx; s_t[w] = src; }
    __syncthreads();
    if (threadIdx.x == 0) {
      float bv = s_v[0]; int bi = s_i[0]; int bt = s_t[0];
      for (int w2 = 1; w2 < 4; ++w2)
        if (better(s_v[w2], s_i[w2], bv, bi)) { bv = s_v[w2]; bi = s_i[w2]; bt = s_t[w2]; }
      s_wv = bv; s_wi = bi; s_wt = bt;
    }
    __syncthreads();
    if (threadIdx.x == s_wt) {
#pragma unroll
      for (int j = 0; j < L - 1; ++j) { tv[j] = tv[j + 1]; ti[j] = ti[j + 1]; }
      tv[L - 1] = -INFINITY; ti[L - 1] = 0x7fffffff;
    }
    if (threadIdx.x == 0) emit(r, s_wv, s_wi);
    __syncthreads();
  }
}

// ---------------- selection: per (q, chunk) top-16 by bf16 cos ----------------
// sims is already cosine-scaled. Group-max prefilter: only run the sorted
// inserts when max of the 8 beats the thread's current 8th-best. Strict
// compare is exact: within a thread the scan index increases monotonically,
// so an equal-value candidate can never have a smaller index than ti[7].
__global__ __launch_bounds__(256) void select_chunks(
    const unsigned short* __restrict__ sims, int* __restrict__ cand,
    int N, int Npitch, int Nc) {
  int q = blockIdx.y;
  int c = blockIdx.x;
  int start = c * Nc;
  int end = start + Nc;
  if (end > N) end = N;
  float tv[8]; int ti[8];
#pragma unroll
  for (int j = 0; j < 8; ++j) { tv[j] = -INFINITY; ti[j] = 0x7fffffff; }
  const unsigned short* row = sims + (size_t)q * Npitch;
  int base = start + threadIdx.x * 8;
  for (; base + 8 <= end; base += 2048) {
    uint4 wv = *(const uint4*)(row + base);
    float f0 = bf2f((unsigned short)(wv.x & 0xffff));
    float f1 = bf2f((unsigned short)(wv.x >> 16));
    float f2 = bf2f((unsigned short)(wv.y & 0xffff));
    float f3 = bf2f((unsigned short)(wv.y >> 16));
    float f4 = bf2f((unsigned short)(wv.z & 0xffff));
    float f5 = bf2f((unsigned short)(wv.z >> 16));
    float f6 = bf2f((unsigned short)(wv.w & 0xffff));
    float f7 = bf2f((unsigned short)(wv.w >> 16));
    float mx = fmaxf(fmaxf(fmaxf(f0, f1), fmaxf(f2, f3)),
                     fmaxf(fmaxf(f4, f5), fmaxf(f6, f7)));
    if (mx > tv[7]) {
      insert_topL<8>(tv, ti, f0, base + 0);
      insert_topL<8>(tv, ti, f1, base + 1);
      insert_topL<8>(tv, ti, f2, base + 2);
      insert_topL<8>(tv, ti, f3, base + 3);
      insert_topL<8>(tv, ti, f4, base + 4);
      insert_topL<8>(tv, ti, f5, base + 5);
      insert_topL<8>(tv, ti, f6, base + 6);
      insert_topL<8>(tv, ti, f7, base + 7);
    }
  }
  // ragged tail
  if (base < end) {
    for (int n = base; n < end; ++n)
      insert_topL<8>(tv, ti, bf2f(row[n]), n);
  }
  int* dst = cand + (size_t)q * NCAND + c * TPC;
  block_extract<8>(tv, ti, TPC, [&](int r, float v, int i) {
    dst[r] = (i == 0x7fffffff) ? 0 : i;
  });
}

// ---------------- rescore candidates in fp32, final top-16 ----------------
__global__ __launch_bounds__(512) void rescore(
    const float* __restrict__ Q, const float* __restrict__ M,
    const float* __restrict__ qn, const int* __restrict__ cand,
    float* __restrict__ out, int N) {
  __shared__ float cosv[NCAND];
  __shared__ int cidx[NCAND];
  int q = blockIdx.x;
  int wave = threadIdx.x >> 6, lane = threadIdx.x & 63;
  const float4* qf4 = (const float4*)(Q + (size_t)q * DDIM);
  float4 qv[4];
#pragma unroll
  for (int t = 0; t < 4; ++t) qv[t] = qf4[t * 64 + lane];
  float qnv = qn[q];
#pragma unroll 1
  for (int i = 0; i < NCAND / 8; ++i) {
    int c = wave * (NCAND / 8) + i;
    int idx = cand[(size_t)q * NCAND + c];
    if (idx < 0 || idx >= N) idx = 0;
    const float4* mf4 = (const float4*)(M + (size_t)idx * DDIM);
    float dot = 0.f, sq = 0.f;
#pragma unroll
    for (int t = 0; t < 4; ++t) {
      float4 m = mf4[t * 64 + lane];
      dot += m.x * qv[t].x + m.y * qv[t].y + m.z * qv[t].z + m.w * qv[t].w;
      sq += m.x * m.x + m.y * m.y + m.z * m.z + m.w * m.w;
    }
#pragma unroll
    for (int o = 32; o > 0; o >>= 1) {
      dot += __shfl_down(dot, o, 64);
      sq += __shfl_down(sq, o, 64);
    }
    if (lane == 0) {
      cosv[c] = dot / fmaxf(qnv * sqrtf(sq), EPSV);
      cidx[c] = idx;
    }
  }
  __syncthreads();
  // final top-16 of the 64 candidates in wave 0
  if (wave == 0) {
    float v0 = cosv[lane];
    int i0 = cidx[lane];
    for (int r = 0; r < 16; ++r) {
      float bv = v0;
      int bi = i0;
      int bs = lane;
#pragma unroll
      for (int o = 32; o > 0; o >>= 1) {
        float ov = __shfl_down(bv, o, 64);
        int oi = __shfl_down(bi, o, 64);
        int os = __shfl_down(bs, o, 64);
        if (better(ov, oi, bv, bi)) { bv = ov; bi = oi; bs = os; }
      }
      bv = __shfl(bv, 0, 64);
      bi = __shfl(bi, 0, 64);
      bs = __shfl(bs, 0, 64);
      if (lane == bs) v0 = -INFINITY;
      if (lane == 0) {
        out[(size_t)q * 16 + r] = bv;
        out[(size_t)BQ * 16 + (size_t)q * 16 + r] = (float)bi;
      }
    }
  }
}

extern "C" void kernel_launch(void* const* d_in, const int* in_sizes, int n_in,
                              void* d_out, int out_size, void* d_ws, size_t ws_size,
                              hipStream_t stream) {
  const float* Q = (const float*)d_in[0];
  const float* M = (const float*)d_in[1];
  int N = in_sizes[1] / DDIM;
  float* out = (float*)d_out;

  int nb = (N + 127) / 128;
  int Npitch = nb * 128;

  char* w = (char*)d_ws;
  size_t off = 0;
  auto alloc = [&](size_t bytes) {
    char* p = w + off;
    off = (off + bytes + 255) & ~(size_t)255;
    return p;
  };
  unsigned short* Qb = (unsigned short*)alloc((size_t)BQ * DDIM * 2);
  float* qn = (float*)alloc((size_t)BQ * 4);
  int* cand = (int*)alloc((size_t)BQ * NCAND * 4);
  unsigned short* sims = (unsigned short*)alloc((size_t)BQ * Npitch * 2);
  (void)ws_size;

  int Nc = (((N + CH - 1) / CH) + 7) & ~7;

  prep_q<<<BQ / 4, 256, 0, stream>>>(Q, Qb, qn);
  gemm_topk<<<nb, 256, 0, stream>>>(M, Qb, sims, N, Npitch);
  select_chunks<<<dim3(CH, BQ), 256, 0, stream>>>(sims, cand, N, Npitch, Nc);
  rescore<<<BQ, 512, 0, stream>>>(Q, M, qn, cand, out, N);
}